// Round 11
// baseline (365.734 us; speedup 1.0000x reference)
//
#include <hip/hip_runtime.h>
#include <hip/hip_bf16.h>

// Problem constants (from reference)
#define N_NODES 100000
#define N_EDGES 1600000
#define N_RELS  8
#define IN_F    64
#define HID_F   64
#define OUT_F   32
#define NSEG    (N_NODES * N_RELS)      // 800000 (node, rel) segments
#define SCAN_EPB 1024                   // elements per scan block (256 thr x 4)
#define SCAN_NB  ((NSEG + SCAN_EPB - 1) / SCAN_EPB)  // 782

typedef __attribute__((ext_vector_type(8))) short short8;   // 8 bf16 = 4 VGPRs
typedef __attribute__((ext_vector_type(4))) float f32x4;

__device__ __forceinline__ float b2f(unsigned short u) {
    return __uint_as_float(((unsigned)u) << 16);
}
__device__ __forceinline__ unsigned short f2b(float f) {
    unsigned u = __float_as_uint(f);
    u += 0x7FFFu + ((u >> 16) & 1u);      // RNE
    return (unsigned short)(u >> 16);
}

#define PREP_W1 (576 * 64)
#define PREP_W2 (576 * 32)
#define PREP_CVT (N_NODES * 64 / 4)
#define PREP_TOT (PREP_W1 + PREP_W2 + PREP_CVT)

// ---------------------------------------------------------------------------
// 1) Histogram + rank, 4 edges/thread (R11): each thread issues 8 coalesced
//    metadata loads, then 4 INDEPENDENT atomics in flight, then 4 coalesced
//    rank stores. Previous form had atomic-MLP=1 per thread behind a
//    dependent-load prep loop — suspected ~95us of latency exposure.
//    Prep conversions still fused (independent work riding along).
// ---------------------------------------------------------------------------
__global__ void k_hist(const int* __restrict__ dst, const int* __restrict__ et,
                       int* __restrict__ cnt, int* __restrict__ rank,
                       const float* __restrict__ W1, const float* __restrict__ root1,
                       const float* __restrict__ W2, const float* __restrict__ root2,
                       const float* __restrict__ x,
                       ushort* __restrict__ Wt1b, ushort* __restrict__ Wt2b,
                       ushort* __restrict__ xb) {
    const int tid = threadIdx.x;
    const int gsz = gridDim.x * 256;
    // prep (independent; overlaps atomic latency)
    for (int j = blockIdx.x * 256 + tid; j < PREP_TOT; j += gsz) {
        if (j < PREP_W1) {
            int o = j / 576, k = j - o * 576;
            float v = (k < 512) ? W1[k * 64 + o] : root1[(k - 512) * 64 + o];
            Wt1b[j] = f2b(v);
        } else if (j < PREP_W1 + PREP_W2) {
            int j2 = j - PREP_W1;
            int o = j2 / 576, k = j2 - o * 576;
            float v = (k < 512) ? W2[k * 32 + o] : root2[(k - 512) * 32 + o];
            Wt2b[j2] = f2b(v);
        } else {
            int j2 = j - PREP_W1 - PREP_W2;
            float4 v = *(const float4*)(x + (size_t)j2 * 4);
            ushort4 u;
            u.x = f2b(v.x); u.y = f2b(v.y); u.z = f2b(v.z); u.w = f2b(v.w);
            *(ushort4*)(xb + (size_t)j2 * 4) = u;
        }
    }
    // 4 edges per thread, stride 256 (each access coalesced)
    const int e0 = blockIdx.x * 1024 + tid;
    int sg[4];
    bool ok[4];
    #pragma unroll
    for (int k = 0; k < 4; ++k) {
        int e = e0 + k * 256;
        ok[k] = (e < N_EDGES);
        sg[k] = ok[k] ? (dst[e] * N_RELS + et[e]) : 0;
    }
    int rk[4];
    #pragma unroll
    for (int k = 0; k < 4; ++k)
        if (ok[k]) rk[k] = atomicAdd(&cnt[sg[k]], 1);    // 4 atomics in flight
    #pragma unroll
    for (int k = 0; k < 4; ++k)
        if (ok[k]) rank[e0 + k * 256] = rk[k];
}

// ---------------------------------------------------------------------------
// 2a) Scan pass A
// ---------------------------------------------------------------------------
__global__ void k_scanA(const int* __restrict__ cnt, int* __restrict__ bsums) {
    __shared__ int red[256];
    int t = threadIdx.x;
    int base = blockIdx.x * SCAN_EPB + t * 4;
    int s = 0;
    #pragma unroll
    for (int j = 0; j < 4; ++j) {
        int idx = base + j;
        if (idx < NSEG) s += cnt[idx];
    }
    red[t] = s;
    __syncthreads();
    for (int st = 128; st > 0; st >>= 1) {
        if (t < st) red[t] += red[t + st];
        __syncthreads();
    }
    if (t == 0) bsums[blockIdx.x] = red[0];
}

// ---------------------------------------------------------------------------
// 2b) Scan pass C
// ---------------------------------------------------------------------------
__global__ void k_scanC(const int* __restrict__ cnt, const int* __restrict__ bsums,
                        int* __restrict__ offs) {
    __shared__ int red[256];
    __shared__ int ts[256];
    int t = threadIdx.x;

    int partial = 0;
    #pragma unroll
    for (int jj = 0; jj < 4; ++jj) {
        int j = t + jj * 256;
        if (j < SCAN_NB && j < (int)blockIdx.x) partial += bsums[j];
    }
    red[t] = partial;
    __syncthreads();
    for (int st = 128; st > 0; st >>= 1) {
        if (t < st) red[t] += red[t + st];
        __syncthreads();
    }
    const int base0 = red[0];

    int base = blockIdx.x * SCAN_EPB + t * 4;
    int v[4];
    int local = 0;
    #pragma unroll
    for (int j = 0; j < 4; ++j) {
        int idx = base + j;
        v[j] = (idx < NSEG) ? cnt[idx] : 0;
        local += v[j];
    }
    ts[t] = local;
    __syncthreads();
    for (int off = 1; off < 256; off <<= 1) {
        int x = (t >= off) ? ts[t - off] : 0;
        __syncthreads();
        ts[t] += x;
        __syncthreads();
    }
    int run = base0 + (ts[t] - local);
    #pragma unroll
    for (int j = 0; j < 4; ++j) {
        int idx = base + j;
        if (idx < NSEG) offs[idx] = run;
        run += v[j];
    }
}

// ---------------------------------------------------------------------------
// 3) Pure scatter (R6 form — single pass, no atomics): R9's atomic-claim
//    variant measured 120us (dependent atomic->store chain); R10's 4-pass
//    dst-windowed variant was neutral-to-worse (re-read cost ate the
//    writeback savings). ssrc[offs[seg]+rank] = (src<<8)|((dst&15)<<4)|rel.
// ---------------------------------------------------------------------------
__global__ void k_scat(const int* __restrict__ src, const int* __restrict__ dst,
                       const int* __restrict__ et, const int* __restrict__ offs,
                       const int* __restrict__ rank, int* __restrict__ ssrc) {
    int e = blockIdx.x * 256 + threadIdx.x;
    if (e < N_EDGES) {
        int r = et[e];
        int d = dst[e];
        int seg = d * N_RELS + r;
        ssrc[offs[seg] + rank[e]] = (src[e] << 8) | ((d & 15) << 4) | r;
    }
}

// ---------------------------------------------------------------------------
// First segment boundary >= p within [s, e] of the (dst,rel)-sorted ssrc
// (boundary: seg byte changes, or e). One vector-load window + ballot.
// ---------------------------------------------------------------------------
__device__ __forceinline__ int seg_bnd(const int* __restrict__ ssrc,
                                       int p, int s, int e, int f) {
    if (p <= s) return s;
    if (p >= e) return e;
    while (true) {
        int q = p + f;
        bool b;
        if (q >= e) b = true;
        else b = (((ssrc[q - 1] ^ ssrc[q]) & 255) != 0);
        unsigned long long m = __ballot(b);
        if (m) return p + __builtin_ctzll(m);
        p += 64;
    }
}

// ---------------------------------------------------------------------------
// 4) Fused layer — R6 verbatim (best measured: 100.5us/layer).
//    Block = 512 thr = 8 waves, 16 nodes. Segment-aligned balanced per-wave
//    stripes; per-edge path: readlane + gather + b2f + v_add + uniform
//    scalar seg-boundary check; flush = plain ds_write to wave-exclusive
//    (node,rel) row. Ledger of failed alternatives (do NOT retry):
//    R3/R5 LDS f32 atomics (~10x slower than ds_write); R7 persistent grid
//    (store amplification + occupancy decay); R8 s_load+lgkmcnt(0)
//    (exposes scalar-cache latency per batch: 153us).
//    Layer floor: random-gather L2-miss concurrency (~85MB compulsory
//    per-XCD fetch at ~1TB/s effective).
// ---------------------------------------------------------------------------
template <int NOUT, bool RELU, typename OutT>
__global__ __launch_bounds__(512, 4) void k_layer(
        const ushort* __restrict__ xb, const int* __restrict__ offs,
        const int* __restrict__ cnt, const int* __restrict__ ssrc,
        const ushort* __restrict__ Wtb, const float* __restrict__ bias,
        OutT* __restrict__ out) {
    constexpr int NT = NOUT / 16;     // n-tiles
    constexpr int S  = 8 / NT;        // k-splits
    __shared__ __align__(16) union {
        float  a32[128 * 68];         // (nib*8+rel) fp32 raw sums, stride 68
        ushort a16[16][584];          // bf16 A tiles (+root @512), 18688B
    } U;
    __shared__ float invT[128];

    float* S32 = U.a32;
    f32x4* pc = (f32x4*)((char*)&U + 18688);  // a32 tail; disjoint from a16

    const int tid = threadIdx.x;
    const int w = tid >> 6;
    const int f = tid & 63;
    const int node0 = blockIdx.x * 16;

    // ---- phase-2 wave assignment; preload first B-frag early ----
    const int t = w % NT, q = w / NT;
    constexpr int cbase = 18 / S, crem = 18 % S;
    const int cs = q * cbase + (q < crem ? q : crem);
    const int ce = cs + cbase + (q < crem ? 1 : 0);
    const int n0 = t * 16;
    const ushort* bptr = Wtb + (n0 + (f & 15)) * 576 + ((f >> 4) * 8);
    short8 bcur = *(const short8*)(bptr + cs * 32);

    // ---- phase 0: zero fp32 region (8704 floats), build inv table ----
    {
        f32x4 z = (f32x4){0.0f, 0.0f, 0.0f, 0.0f};
        #pragma unroll
        for (int k = 0; k < 4; ++k)                       // consecutive 16B:
            *(f32x4*)(S32 + (tid + k * 512) * 4) = z;     // conflict-free
        S32[8192 + tid] = 0.0f;                           // tail 512 floats
        if (tid < 128) {
            int c = cnt[node0 * 8 + tid];
            invT[tid] = 1.0f / (float)(c > 0 ? c : 1);
        }
    }
    const int start = offs[node0 * 8];
    const int end = (node0 + 16 >= N_NODES) ? N_EDGES : offs[(node0 + 16) * 8];
    __syncthreads();

    // ---- phase 1: segment-aligned balanced per-wave stripes ----
    {
        const int tot = end - start;
        const int ebase = tot >> 3, erem = tot & 7;
        const int i0 = start + w * ebase + (w < erem ? w : erem);
        const int i1 = i0 + ebase + (w < erem ? 1 : 0);
        const int bs = seg_bnd(ssrc, i0, start, end, f);
        const int be = seg_bnd(ssrc, i1, start, end, f);

        float running = 0.0f;
        int pseg = 255;                       // pad sentinel: never flushed
        for (int cb = bs; cb < be; cb += 64) {
            int n = be - cb;
            if (n > 64) n = 64;
            int pk = 0xFF;                    // pad: seg=255, src=0
            if (f < n) pk = ssrc[cb + f];
            for (int e = 0; e < n; e += 16) {
                int pv[16];
                float xv[16];
                #pragma unroll
                for (int i = 0; i < 16; ++i)
                    pv[i] = __builtin_amdgcn_readlane(pk, e + i);   // SGPR
                #pragma unroll
                for (int i = 0; i < 16; ++i)
                    xv[i] = b2f(xb[(size_t)((unsigned)pv[i] >> 8) * 64 + f]);
                #pragma unroll
                for (int i = 0; i < 16; ++i) {
                    const int sg = pv[i] & 255;           // seg id, non-decr.
                    if (sg != pseg) {                     // uniform scalar br.
                        if (pseg != 255) {                // PLAIN write flush:
                            const int row = ((pseg >> 4) << 3) | (pseg & 7);
                            S32[row * 68 + f] = running;  // wave-exclusive row
                        }
                        running = 0.0f;
                        pseg = sg;
                    }
                    running += xv[i];         // pads pollute only seg-255 runs
                }
            }
        }
        if (pseg != 255) {                    // final flush
            const int row = ((pseg >> 4) << 3) | (pseg & 7);
            S32[row * 68 + f] = running;
        }
    }
    __syncthreads();

    // ---- phase 1.5: normalize + bf16-convert, in-place via reg staging ----
    float rv[16];
    {
        const int row = tid >> 2;            // 0..127 (nib*8+rel)
        const int fb = (tid & 3) * 16;
        const float inv = invT[row];
        #pragma unroll
        for (int k = 0; k < 4; ++k) {
            f32x4 v = *(f32x4*)(S32 + row * 68 + fb + k * 4);
            rv[k * 4 + 0] = v.x * inv; rv[k * 4 + 1] = v.y * inv;
            rv[k * 4 + 2] = v.z * inv; rv[k * 4 + 3] = v.w * inv;
        }
    }
    __syncthreads();                          // all fp32 reads done
    {
        const int row = tid >> 2;
        const int nib = row >> 3, rel = row & 7;
        const int fb = (tid & 3) * 16;
        ushort* dp = &U.a16[nib][rel * 64 + fb];
        short8 o0, o1;
        #pragma unroll
        for (int k = 0; k < 8; ++k) o0[k] = (short)f2b(rv[k]);
        #pragma unroll
        for (int k = 0; k < 8; ++k) o1[k] = (short)f2b(rv[8 + k]);
        *(short8*)dp = o0;
        *(short8*)(dp + 8) = o1;
        // root rows: 2 bf16 per thread straight from input
        const int m = tid >> 5, f2 = (tid & 31) * 2;
        uint xr = *(const uint*)(xb + (size_t)(node0 + m) * 64 + f2);
        *(uint*)&U.a16[m][512 + f2] = xr;
    }
    __syncthreads();

    // ---- Phase 2: MFMA over this wave's chunks (software-pipelined B) ----
    f32x4 acc = (f32x4){0.0f, 0.0f, 0.0f, 0.0f};
    const ushort* aptr = &U.a16[f & 15][(f >> 4) * 8];
    for (int c = cs; c < ce; ++c) {
        short8 bnext = bcur;
        if (c + 1 < ce) bnext = *(const short8*)(bptr + (c + 1) * 32);
        short8 af = *(const short8*)(aptr + c * 32);
        acc = __builtin_amdgcn_mfma_f32_16x16x32_bf16(af, bcur, acc, 0, 0, 0);
        bcur = bnext;
    }

    // ---- Phase 3: reduce k-splits, bias (+ReLU), store ----
    if (q > 0) pc[(w - NT) * 64 + f] = acc;   // writes a32 tail: disjoint
    __syncthreads();                          // from a16 still read above
    if (q == 0) {
        #pragma unroll
        for (int j = 1; j < S; ++j) {
            f32x4 p = pc[(t + NT * (j - 1)) * 64 + f];
            acc.x += p.x; acc.y += p.y; acc.z += p.z; acc.w += p.w;
        }
        const int col = f & 15;
        const float bs2 = bias[n0 + col];
        const int mrow = (f >> 4) * 4;   // C/D: row=(lane>>4)*4+reg, col=lane&15
        #pragma unroll
        for (int i = 0; i < 4; ++i) {
            float v = acc[i] + bs2;
            if (RELU) v = fmaxf(v, 0.0f);
            size_t oi = (size_t)(node0 + mrow + i) * NOUT + n0 + col;
            if constexpr (sizeof(OutT) == 2) out[oi] = (OutT)f2b(v);
            else                             out[oi] = (OutT)v;
        }
    }
}

// ---------------------------------------------------------------------------
// Launch: 7 dispatches (memset, hist+prep, scanA, scanC, scat, layer1, layer2)
// ---------------------------------------------------------------------------
extern "C" void kernel_launch(void* const* d_in, const int* in_sizes, int n_in,
                              void* d_out, int out_size, void* d_ws, size_t ws_size,
                              hipStream_t stream) {
    const float* x     = (const float*)d_in[0];
    const int*   ei    = (const int*)d_in[1];
    const int*   et    = (const int*)d_in[2];
    const float* W1    = (const float*)d_in[3];
    const float* root1 = (const float*)d_in[4];
    const float* b1    = (const float*)d_in[5];
    const float* W2    = (const float*)d_in[6];
    const float* root2 = (const float*)d_in[7];
    const float* b2    = (const float*)d_in[8];
    float* out = (float*)d_out;

    const int* src = ei;            // edge_index[0]
    const int* dst = ei + N_EDGES;  // edge_index[1]

    // Workspace layout (~38.5 MB):
    //   cnt 3.2M | offs 3.2M | bsums 4K | ssrc 6.4M | xb 12.8M |
    //   h1b 12.8M (rank overlaps its first 6.4M — dead before h1b written) |
    //   Wt1b 73.7K | Wt2b 36.9K
    char* ws = (char*)d_ws;
    int*    cnt   = (int*)(ws);
    int*    offs  = (int*)(ws + (size_t)NSEG * 4);
    int*    bsums = (int*)(ws + (size_t)NSEG * 8);
    int*    ssrc  = (int*)(ws + (size_t)NSEG * 8 + 4096);
    ushort* xb    = (ushort*)(ws + (size_t)NSEG * 8 + 4096 + (size_t)N_EDGES * 4);
    ushort* h1b   = (ushort*)((char*)xb + (size_t)N_NODES * 64 * 2);
    int*    rank  = (int*)h1b;   // overlap: rank dead after k_scat
    ushort* Wt1b  = (ushort*)((char*)h1b + (size_t)N_NODES * 64 * 2);
    ushort* Wt2b  = (ushort*)((char*)Wt1b + (size_t)PREP_W1 * 2);

    (void)hipMemsetAsync(cnt, 0, (size_t)NSEG * 4, stream);

    int eb = (N_EDGES + 255) / 256;
    int hb = (N_EDGES + 1023) / 1024;         // 4 edges/thread
    k_hist<<<hb, 256, 0, stream>>>(dst, et, cnt, rank,
                                   W1, root1, W2, root2, x, Wt1b, Wt2b, xb);
    k_scanA<<<SCAN_NB, 256, 0, stream>>>(cnt, bsums);
    k_scanC<<<SCAN_NB, 256, 0, stream>>>(cnt, bsums, offs);
    k_scat<<<eb, 256, 0, stream>>>(src, dst, et, offs, rank, ssrc);

    // Layer 1: xb -> h1b (bf16, ReLU), NOUT=64
    k_layer<64, true, ushort><<<N_NODES / 16, 512, 0, stream>>>(
        xb, offs, cnt, ssrc, Wt1b, b1, h1b);
    // Layer 2: h1b -> out (fp32), NOUT=32
    k_layer<32, false, float><<<N_NODES / 16, 512, 0, stream>>>(
        h1b, offs, cnt, ssrc, Wt2b, b2, out);
}

// Round 12
// 356.082 us; speedup vs baseline: 1.0271x; 1.0271x over previous
//
#include <hip/hip_runtime.h>
#include <hip/hip_bf16.h>

// Problem constants (from reference)
#define N_NODES 100000
#define N_EDGES 1600000
#define N_RELS  8
#define IN_F    64
#define HID_F   64
#define OUT_F   32
#define NSEG    (N_NODES * N_RELS)      // 800000 (node, rel) segments
#define SCAN_EPB 1024                   // elements per scan block (256 thr x 4)
#define SCAN_NB  ((NSEG + SCAN_EPB - 1) / SCAN_EPB)  // 782

typedef __attribute__((ext_vector_type(8))) short short8;   // 8 bf16 = 4 VGPRs
typedef __attribute__((ext_vector_type(4))) float f32x4;

__device__ __forceinline__ float b2f(unsigned short u) {
    return __uint_as_float(((unsigned)u) << 16);
}
__device__ __forceinline__ unsigned short f2b(float f) {
    unsigned u = __float_as_uint(f);
    u += 0x7FFFu + ((u >> 16) & 1u);      // RNE
    return (unsigned short)(u >> 16);
}

#define PREP_W1 (576 * 64)
#define PREP_W2 (576 * 32)
#define PREP_CVT (N_NODES * 64 / 4)
#define PREP_TOT (PREP_W1 + PREP_W2 + PREP_CVT)

// ---------------------------------------------------------------------------
// 1) Histogram + rank (atomic-free scatter later), with prep work fused in.
//    R11 lesson: hist is L2-atomic-throughput-bound — 4 atomics/thread in
//    flight was neutral. Keep the simple 1-edge/thread form.
// ---------------------------------------------------------------------------
__global__ void k_hist(const int* __restrict__ dst, const int* __restrict__ et,
                       int* __restrict__ cnt, int* __restrict__ rank,
                       const float* __restrict__ W1, const float* __restrict__ root1,
                       const float* __restrict__ W2, const float* __restrict__ root2,
                       const float* __restrict__ x,
                       ushort* __restrict__ Wt1b, ushort* __restrict__ Wt2b,
                       ushort* __restrict__ xb) {
    const int e = blockIdx.x * 256 + threadIdx.x;
    const int gsz = gridDim.x * 256;
    for (int j = e; j < PREP_TOT; j += gsz) {
        if (j < PREP_W1) {
            int o = j / 576, k = j - o * 576;
            float v = (k < 512) ? W1[k * 64 + o] : root1[(k - 512) * 64 + o];
            Wt1b[j] = f2b(v);
        } else if (j < PREP_W1 + PREP_W2) {
            int j2 = j - PREP_W1;
            int o = j2 / 576, k = j2 - o * 576;
            float v = (k < 512) ? W2[k * 32 + o] : root2[(k - 512) * 32 + o];
            Wt2b[j2] = f2b(v);
        } else {
            int j2 = j - PREP_W1 - PREP_W2;
            float4 v = *(const float4*)(x + (size_t)j2 * 4);
            ushort4 u;
            u.x = f2b(v.x); u.y = f2b(v.y); u.z = f2b(v.z); u.w = f2b(v.w);
            *(ushort4*)(xb + (size_t)j2 * 4) = u;
        }
    }
    if (e < N_EDGES) {
        int seg = dst[e] * N_RELS + et[e];
        rank[e] = atomicAdd(&cnt[seg], 1);
    }
}

// ---------------------------------------------------------------------------
// 2a) Scan pass A
// ---------------------------------------------------------------------------
__global__ void k_scanA(const int* __restrict__ cnt, int* __restrict__ bsums) {
    __shared__ int red[256];
    int t = threadIdx.x;
    int base = blockIdx.x * SCAN_EPB + t * 4;
    int s = 0;
    #pragma unroll
    for (int j = 0; j < 4; ++j) {
        int idx = base + j;
        if (idx < NSEG) s += cnt[idx];
    }
    red[t] = s;
    __syncthreads();
    for (int st = 128; st > 0; st >>= 1) {
        if (t < st) red[t] += red[t + st];
        __syncthreads();
    }
    if (t == 0) bsums[blockIdx.x] = red[0];
}

// ---------------------------------------------------------------------------
// 2b) Scan pass C
// ---------------------------------------------------------------------------
__global__ void k_scanC(const int* __restrict__ cnt, const int* __restrict__ bsums,
                        int* __restrict__ offs) {
    __shared__ int red[256];
    __shared__ int ts[256];
    int t = threadIdx.x;

    int partial = 0;
    #pragma unroll
    for (int jj = 0; jj < 4; ++jj) {
        int j = t + jj * 256;
        if (j < SCAN_NB && j < (int)blockIdx.x) partial += bsums[j];
    }
    red[t] = partial;
    __syncthreads();
    for (int st = 128; st > 0; st >>= 1) {
        if (t < st) red[t] += red[t + st];
        __syncthreads();
    }
    const int base0 = red[0];

    int base = blockIdx.x * SCAN_EPB + t * 4;
    int v[4];
    int local = 0;
    #pragma unroll
    for (int j = 0; j < 4; ++j) {
        int idx = base + j;
        v[j] = (idx < NSEG) ? cnt[idx] : 0;
        local += v[j];
    }
    ts[t] = local;
    __syncthreads();
    for (int off = 1; off < 256; off <<= 1) {
        int x = (t >= off) ? ts[t - off] : 0;
        __syncthreads();
        ts[t] += x;
        __syncthreads();
    }
    int run = base0 + (ts[t] - local);
    #pragma unroll
    for (int j = 0; j < 4; ++j) {
        int idx = base + j;
        if (idx < NSEG) offs[idx] = run;
        run += v[j];
    }
}

// ---------------------------------------------------------------------------
// 3) Pure scatter (single pass, rank-based, no atomics): R9's atomic-claim
//    variant measured 120us; R10's 4-pass dst-windowed variant was neutral
//    (re-read cost ate the writeback savings). The ~100MB line ping-pong is
//    inherent to the global scatter that IS the sort.
// ---------------------------------------------------------------------------
__global__ void k_scat(const int* __restrict__ src, const int* __restrict__ dst,
                       const int* __restrict__ et, const int* __restrict__ offs,
                       const int* __restrict__ rank, int* __restrict__ ssrc) {
    int e = blockIdx.x * 256 + threadIdx.x;
    if (e < N_EDGES) {
        int r = et[e];
        int d = dst[e];
        int seg = d * N_RELS + r;
        ssrc[offs[seg] + rank[e]] = (src[e] << 8) | ((d & 15) << 4) | r;
    }
}

// ---------------------------------------------------------------------------
// First segment boundary >= p within [s, e] of the (dst,rel)-sorted ssrc
// (boundary: seg byte changes, or e). One vector-load window + ballot.
// ---------------------------------------------------------------------------
__device__ __forceinline__ int seg_bnd(const int* __restrict__ ssrc,
                                       int p, int s, int e, int f) {
    if (p <= s) return s;
    if (p >= e) return e;
    while (true) {
        int q = p + f;
        bool b;
        if (q >= e) b = true;
        else b = (((ssrc[q - 1] ^ ssrc[q]) & 255) != 0);
        unsigned long long m = __ballot(b);
        if (m) return p + __builtin_ctzll(m);
        p += 64;
    }
}

// ---------------------------------------------------------------------------
// 4) Fused layer — R6 verbatim (best measured: ~100us/layer).
//    Block = 512 thr = 8 waves, 16 nodes. Segment-aligned balanced per-wave
//    stripes; per-edge path: readlane + gather + b2f + v_add + uniform
//    scalar seg-boundary check; flush = plain ds_write to wave-exclusive
//    (node,rel) row. Ledger of failed alternatives (do NOT retry):
//    R3/R5 LDS f32 atomics (~10x slower than ds_write); R7 persistent grid
//    (store amplification + occupancy decay); R8 s_load+lgkmcnt(0)
//    (exposes scalar-cache latency per batch: 153us).
//    Layer floor: random-gather L2-miss concurrency (~85MB compulsory
//    per-XCD fetch at ~1TB/s effective).
// ---------------------------------------------------------------------------
template <int NOUT, bool RELU, typename OutT>
__global__ __launch_bounds__(512, 4) void k_layer(
        const ushort* __restrict__ xb, const int* __restrict__ offs,
        const int* __restrict__ cnt, const int* __restrict__ ssrc,
        const ushort* __restrict__ Wtb, const float* __restrict__ bias,
        OutT* __restrict__ out) {
    constexpr int NT = NOUT / 16;     // n-tiles
    constexpr int S  = 8 / NT;        // k-splits
    __shared__ __align__(16) union {
        float  a32[128 * 68];         // (nib*8+rel) fp32 raw sums, stride 68
        ushort a16[16][584];          // bf16 A tiles (+root @512), 18688B
    } U;
    __shared__ float invT[128];

    float* S32 = U.a32;
    f32x4* pc = (f32x4*)((char*)&U + 18688);  // a32 tail; disjoint from a16

    const int tid = threadIdx.x;
    const int w = tid >> 6;
    const int f = tid & 63;
    const int node0 = blockIdx.x * 16;

    // ---- phase-2 wave assignment; preload first B-frag early ----
    const int t = w % NT, q = w / NT;
    constexpr int cbase = 18 / S, crem = 18 % S;
    const int cs = q * cbase + (q < crem ? q : crem);
    const int ce = cs + cbase + (q < crem ? 1 : 0);
    const int n0 = t * 16;
    const ushort* bptr = Wtb + (n0 + (f & 15)) * 576 + ((f >> 4) * 8);
    short8 bcur = *(const short8*)(bptr + cs * 32);

    // ---- phase 0: zero fp32 region (8704 floats), build inv table ----
    {
        f32x4 z = (f32x4){0.0f, 0.0f, 0.0f, 0.0f};
        #pragma unroll
        for (int k = 0; k < 4; ++k)                       // consecutive 16B:
            *(f32x4*)(S32 + (tid + k * 512) * 4) = z;     // conflict-free
        S32[8192 + tid] = 0.0f;                           // tail 512 floats
        if (tid < 128) {
            int c = cnt[node0 * 8 + tid];
            invT[tid] = 1.0f / (float)(c > 0 ? c : 1);
        }
    }
    const int start = offs[node0 * 8];
    const int end = (node0 + 16 >= N_NODES) ? N_EDGES : offs[(node0 + 16) * 8];
    __syncthreads();

    // ---- phase 1: segment-aligned balanced per-wave stripes ----
    {
        const int tot = end - start;
        const int ebase = tot >> 3, erem = tot & 7;
        const int i0 = start + w * ebase + (w < erem ? w : erem);
        const int i1 = i0 + ebase + (w < erem ? 1 : 0);
        const int bs = seg_bnd(ssrc, i0, start, end, f);
        const int be = seg_bnd(ssrc, i1, start, end, f);

        float running = 0.0f;
        int pseg = 255;                       // pad sentinel: never flushed
        for (int cb = bs; cb < be; cb += 64) {
            int n = be - cb;
            if (n > 64) n = 64;
            int pk = 0xFF;                    // pad: seg=255, src=0
            if (f < n) pk = ssrc[cb + f];
            for (int e = 0; e < n; e += 16) {
                int pv[16];
                float xv[16];
                #pragma unroll
                for (int i = 0; i < 16; ++i)
                    pv[i] = __builtin_amdgcn_readlane(pk, e + i);   // SGPR
                #pragma unroll
                for (int i = 0; i < 16; ++i)
                    xv[i] = b2f(xb[(size_t)((unsigned)pv[i] >> 8) * 64 + f]);
                #pragma unroll
                for (int i = 0; i < 16; ++i) {
                    const int sg = pv[i] & 255;           // seg id, non-decr.
                    if (sg != pseg) {                     // uniform scalar br.
                        if (pseg != 255) {                // PLAIN write flush:
                            const int row = ((pseg >> 4) << 3) | (pseg & 7);
                            S32[row * 68 + f] = running;  // wave-exclusive row
                        }
                        running = 0.0f;
                        pseg = sg;
                    }
                    running += xv[i];         // pads pollute only seg-255 runs
                }
            }
        }
        if (pseg != 255) {                    // final flush
            const int row = ((pseg >> 4) << 3) | (pseg & 7);
            S32[row * 68 + f] = running;
        }
    }
    __syncthreads();

    // ---- phase 1.5: normalize + bf16-convert, in-place via reg staging ----
    float rv[16];
    {
        const int row = tid >> 2;            // 0..127 (nib*8+rel)
        const int fb = (tid & 3) * 16;
        const float inv = invT[row];
        #pragma unroll
        for (int k = 0; k < 4; ++k) {
            f32x4 v = *(f32x4*)(S32 + row * 68 + fb + k * 4);
            rv[k * 4 + 0] = v.x * inv; rv[k * 4 + 1] = v.y * inv;
            rv[k * 4 + 2] = v.z * inv; rv[k * 4 + 3] = v.w * inv;
        }
    }
    __syncthreads();                          // all fp32 reads done
    {
        const int row = tid >> 2;
        const int nib = row >> 3, rel = row & 7;
        const int fb = (tid & 3) * 16;
        ushort* dp = &U.a16[nib][rel * 64 + fb];
        short8 o0, o1;
        #pragma unroll
        for (int k = 0; k < 8; ++k) o0[k] = (short)f2b(rv[k]);
        #pragma unroll
        for (int k = 0; k < 8; ++k) o1[k] = (short)f2b(rv[8 + k]);
        *(short8*)dp = o0;
        *(short8*)(dp + 8) = o1;
        // root rows: 2 bf16 per thread straight from input
        const int m = tid >> 5, f2 = (tid & 31) * 2;
        uint xr = *(const uint*)(xb + (size_t)(node0 + m) * 64 + f2);
        *(uint*)&U.a16[m][512 + f2] = xr;
    }
    __syncthreads();

    // ---- Phase 2: MFMA over this wave's chunks (software-pipelined B) ----
    f32x4 acc = (f32x4){0.0f, 0.0f, 0.0f, 0.0f};
    const ushort* aptr = &U.a16[f & 15][(f >> 4) * 8];
    for (int c = cs; c < ce; ++c) {
        short8 bnext = bcur;
        if (c + 1 < ce) bnext = *(const short8*)(bptr + (c + 1) * 32);
        short8 af = *(const short8*)(aptr + c * 32);
        acc = __builtin_amdgcn_mfma_f32_16x16x32_bf16(af, bcur, acc, 0, 0, 0);
        bcur = bnext;
    }

    // ---- Phase 3: reduce k-splits, bias (+ReLU), store ----
    if (q > 0) pc[(w - NT) * 64 + f] = acc;   // writes a32 tail: disjoint
    __syncthreads();                          // from a16 still read above
    if (q == 0) {
        #pragma unroll
        for (int j = 1; j < S; ++j) {
            f32x4 p = pc[(t + NT * (j - 1)) * 64 + f];
            acc.x += p.x; acc.y += p.y; acc.z += p.z; acc.w += p.w;
        }
        const int col = f & 15;
        const float bs2 = bias[n0 + col];
        const int mrow = (f >> 4) * 4;   // C/D: row=(lane>>4)*4+reg, col=lane&15
        #pragma unroll
        for (int i = 0; i < 4; ++i) {
            float v = acc[i] + bs2;
            if (RELU) v = fmaxf(v, 0.0f);
            size_t oi = (size_t)(node0 + mrow + i) * NOUT + n0 + col;
            if constexpr (sizeof(OutT) == 2) out[oi] = (OutT)f2b(v);
            else                             out[oi] = (OutT)v;
        }
    }
}

// ---------------------------------------------------------------------------
// Launch: 7 dispatches (memset, hist+prep, scanA, scanC, scat, layer1, layer2)
// ---------------------------------------------------------------------------
extern "C" void kernel_launch(void* const* d_in, const int* in_sizes, int n_in,
                              void* d_out, int out_size, void* d_ws, size_t ws_size,
                              hipStream_t stream) {
    const float* x     = (const float*)d_in[0];
    const int*   ei    = (const int*)d_in[1];
    const int*   et    = (const int*)d_in[2];
    const float* W1    = (const float*)d_in[3];
    const float* root1 = (const float*)d_in[4];
    const float* b1    = (const float*)d_in[5];
    const float* W2    = (const float*)d_in[6];
    const float* root2 = (const float*)d_in[7];
    const float* b2    = (const float*)d_in[8];
    float* out = (float*)d_out;

    const int* src = ei;            // edge_index[0]
    const int* dst = ei + N_EDGES;  // edge_index[1]

    // Workspace layout (~38.5 MB):
    //   cnt 3.2M | offs 3.2M | bsums 4K | ssrc 6.4M | xb 12.8M |
    //   h1b 12.8M (rank overlaps its first 6.4M — dead before h1b written) |
    //   Wt1b 73.7K | Wt2b 36.9K
    char* ws = (char*)d_ws;
    int*    cnt   = (int*)(ws);
    int*    offs  = (int*)(ws + (size_t)NSEG * 4);
    int*    bsums = (int*)(ws + (size_t)NSEG * 8);
    int*    ssrc  = (int*)(ws + (size_t)NSEG * 8 + 4096);
    ushort* xb    = (ushort*)(ws + (size_t)NSEG * 8 + 4096 + (size_t)N_EDGES * 4);
    ushort* h1b   = (ushort*)((char*)xb + (size_t)N_NODES * 64 * 2);
    int*    rank  = (int*)h1b;   // overlap: rank dead after k_scat
    ushort* Wt1b  = (ushort*)((char*)h1b + (size_t)N_NODES * 64 * 2);
    ushort* Wt2b  = (ushort*)((char*)Wt1b + (size_t)PREP_W1 * 2);

    (void)hipMemsetAsync(cnt, 0, (size_t)NSEG * 4, stream);

    int eb = (N_EDGES + 255) / 256;
    k_hist<<<eb, 256, 0, stream>>>(dst, et, cnt, rank,
                                   W1, root1, W2, root2, x, Wt1b, Wt2b, xb);
    k_scanA<<<SCAN_NB, 256, 0, stream>>>(cnt, bsums);
    k_scanC<<<SCAN_NB, 256, 0, stream>>>(cnt, bsums, offs);
    k_scat<<<eb, 256, 0, stream>>>(src, dst, et, offs, rank, ssrc);

    // Layer 1: xb -> h1b (bf16, ReLU), NOUT=64
    k_layer<64, true, ushort><<<N_NODES / 16, 512, 0, stream>>>(
        xb, offs, cnt, ssrc, Wt1b, b1, h1b);
    // Layer 2: h1b -> out (fp32), NOUT=32
    k_layer<32, false, float><<<N_NODES / 16, 512, 0, stream>>>(
        h1b, offs, cnt, ssrc, Wt2b, b2, out);
}